// Round 5
// baseline (877.055 us; speedup 1.0000x reference)
//
#include <hip/hip_runtime.h>
#include <hip/hip_bf16.h>

typedef unsigned short u16;
typedef unsigned int u32;
typedef short bf16x8 __attribute__((ext_vector_type(8)));
typedef float f32x4 __attribute__((ext_vector_type(4)));

#define EPSV 1e-5f
// ws byte layout
#define WS_A3    0                       // 128*8 f32
#define WS_C3    4096                    // 128 f32
#define WS_C3BF  4608                    // 128 bf16
#define WS_WB    4864                    // 128*128 bf16
#define WS_WCAT  37632                   // 128*160 bf16 [wf2 | A1 | bias | 0]
#define WS_Q     78592                   // 33.55 MB bf16 q = A3@x
#define WS_NE    (78592 + 33554432)      // 33.55 MB bf16 NE

union U4 { uint4 q; bf16x8 v; };

__device__ __forceinline__ u16 f2bf(float f) {
    union { __hip_bfloat16 h; u16 u; } cv;
    cv.h = __float2bfloat16(f);
    return cv.u;
}
__device__ __forceinline__ u32 pack_rne(float a, float b) {
    u32 ua = __float_as_uint(a), ub = __float_as_uint(b);
    ua = ua + 0x7FFFu + ((ua >> 16) & 1u);
    ub = ub + 0x7FFFu + ((ub >> 16) & 1u);
    return (ua >> 16) | (ub & 0xFFFF0000u);
}
// z = relu(bf(a_half) + bf(d_half)), packed bf16 (round-half-up + v_perm)
__device__ __forceinline__ u32 zpair(u32 a, u32 d) {
    float lo = __uint_as_float(a << 16) + __uint_as_float(d << 16);
    float hi = __uint_as_float(a & 0xFFFF0000u) + __uint_as_float(d & 0xFFFF0000u);
    lo = fmaxf(lo, 0.f);
    hi = fmaxf(hi, 0.f);
    return __builtin_amdgcn_perm(__float_as_uint(hi) + 0x8000u,
                                 __float_as_uint(lo) + 0x8000u, 0x07060302u);
}
// d = bf(c_half) - bf(q_half), packed bf16
__device__ __forceinline__ u32 dpair(u32 c, u32 qc) {
    float lo = __uint_as_float(c << 16) - __uint_as_float(qc << 16);
    float hi = __uint_as_float(c & 0xFFFF0000u) - __uint_as_float(qc & 0xFFFF0000u);
    return pack_rne(lo, hi);
}

// ---------------- prep: fold constants (fully parallel, LDS-staged) ----------------
__global__ __launch_bounds__(256) void prep_kernel(
    const float* g1, const float* b1, const float* m1, const float* v1,
    const float* w1, const float* c1b,
    const float* g2, const float* b2, const float* m2, const float* v2,
    const float* wA,
    const float* g3, const float* b3, const float* m3, const float* v3,
    const float* wB, const float* wf, const float* bfv,
    float* ws, u16* c3bf, u16* wBh, u16* Wc)
{
    __shared__ float wfL[16384];     // wf left half, 64 KB
    __shared__ float w1s[1024];
    __shared__ float c1s[128];
    __shared__ float s1[8], be1[8], s2[8], be2[8];
    __shared__ float w1fS[128][8];
    __shared__ float cbS[128];
    int t = threadIdx.x;

    // stage (coalesced, latency-pipelined across 256 threads)
    for (int i = t; i < 16384; i += 256) wfL[i] = wf[((i >> 7) << 8) + (i & 127)];
    for (int i = t; i < 1024; i += 256) w1s[i] = w1[i];
    if (t < 128) c1s[t] = c1b[t];
    if (t < 8) {
        float s = g1[t] * rsqrtf(v1[t] + EPSV); s1[t] = s; be1[t] = b1[t] - m1[t] * s;
        float u = g2[t] * rsqrtf(v2[t] + EPSV); s2[t] = u; be2[t] = b2[t] - m2[t] * u;
    }
    __syncthreads();

    // fold wf_left @ [w1 | c1b]: thread (o, half) does 4 i's (+ cb on half 1)
    {
        int o = t >> 1, half = t & 1;
        float a0 = 0.f, a1 = 0.f, a2 = 0.f, a3 = 0.f, cb = 0.f;
        const float* wro = wfL + o * 128;
        int i0 = half * 4;
        for (int c = 0; c < 128; c++) {
            float f = wro[c];
            const float* wr = w1s + c * 8 + i0;
            a0 += f * wr[0]; a1 += f * wr[1]; a2 += f * wr[2]; a3 += f * wr[3];
            if (half) cb += f * c1s[c];
        }
        w1fS[o][i0] = a0; w1fS[o][i0 + 1] = a1; w1fS[o][i0 + 2] = a2; w1fS[o][i0 + 3] = a3;
        if (half) cbS[o] = cb;
    }
    __syncthreads();

    if (t < 128) {
        int o = t;
        float s3 = g3[o] * rsqrtf(v3[o] + EPSV);
        float be3 = b3[o] - m3[o] * s3;
        float* A3 = ws;
        float* c3 = ws + 1024;
        float csum = 0.f;
        #pragma unroll
        for (int i = 0; i < 8; i++) {
            float w = wA[o * 8 + i];
            A3[o * 8 + i] = s3 * w * s2[i] * s1[i];
            csum += w * be2[i];
        }
        float c3v = s3 * csum + be3;
        c3[o] = c3v;
        c3bf[o] = f2bf(c3v);

        float bs = bfv[o] + cbS[o];
        #pragma unroll
        for (int i = 0; i < 8; i++) {
            float w1f = w1fS[o][i];
            bs += w1f * be1[i];
            Wc[o * 160 + 128 + i] = f2bf(w1f * s1[i]);
        }
        Wc[o * 160 + 136] = f2bf(bs);
        for (int k = 137; k < 160; k++) Wc[o * 160 + k] = 0;
    }
    // Wcat wf2 block: 16384 elems, coalesced grid-stride
    for (int j = t; j < 16384; j += 256) {
        int o = j >> 7, c = j & 127;
        Wc[o * 160 + c] = f2bf(wf[o * 256 + 128 + c]);
    }
    // wB cast: 8192 packed u32, coalesced
    {
        u32* wbo = (u32*)wBh;
        for (int j = t; j < 8192; j += 256)
            wbo[j] = pack_rne(wB[2 * j], wB[2 * j + 1]);
    }
}

// ---------------- q = A3 @ x (bf16) --------------------
__global__ __launch_bounds__(256) void q_kernel(const float* __restrict__ x,
                                                const float* __restrict__ ws,
                                                u16* __restrict__ q)
{
    int t = blockIdx.x * 256 + threadIdx.x;
    int pt = t >> 6;
    int o = (t & 63) * 2;
    int b = pt >> 16, n = pt & 65535;
    const float* A3 = ws;
    float xv[8];
    #pragma unroll
    for (int i = 0; i < 8; i++) xv[i] = x[(((b << 3) + i) << 16) | n];
    float q0 = 0.f, q1 = 0.f;
    #pragma unroll
    for (int i = 0; i < 8; i++) {
        q0 += A3[o * 8 + i] * xv[i];
        q1 += A3[(o + 1) * 8 + i] * xv[i];
    }
    ((u32*)q)[t] = pack_rne(q0, q1);
}

// ---------------- heavy: 1-wave blocks, barrier-free, LDS-free edge-conv ----------
// wave = 16 points; A-frag (m=slot, k=channel) built in registers from gathered
// q rows; wB^T fragments persistent in VGPRs; 32 MFMA/point; max over slots =
// rows via 2 shfl_xor; NE written bf16 to global. 64-thr blocks -> 4 waves/SIMD.
__global__ __launch_bounds__(64, 4) void heavy_kernel(
    const u16* __restrict__ q, const int* __restrict__ nbr,
    const u16* __restrict__ wBh, const u16* __restrict__ c3bf,
    u16* __restrict__ NEg)
{
    const uint4* qv = (const uint4*)q;
    int l = threadIdx.x;               // 0..63
    int quad = l >> 4, l15 = l & 15;

    // persistent wB^T B-fragments: B[n=o=nt*16+l15][k=kt*32+quad*8+j]
    bf16x8 wBf[8][4];
    #pragma unroll
    for (int nt = 0; nt < 8; nt++)
        #pragma unroll
        for (int kt = 0; kt < 4; kt++) {
            U4 u; u.q = *(const uint4*)(wBh + (nt * 16 + l15) * 128 + kt * 32 + quad * 8);
            wBf[nt][kt] = u.v;
        }
    // persistent packed c3 at this lane's channels (kt*32+quad*8 ..+7)
    uint4 c3pk[4];
    #pragma unroll
    for (int kt = 0; kt < 4; kt++)
        c3pk[kt] = *(const uint4*)(c3bf + kt * 32 + quad * 8);

    int pbase = blockIdx.x * 16;       // 16 points per wave, batch-aligned
    int b = pbase >> 16;
    int n0 = pbase & 65535;
    int srow = (l15 < 15) ? l15 + 1 : 1;   // slot 15 duplicates neighbor row 1
    const int* nrow = nbr + ((((b << 4) + srow) << 16) + n0);

    // software pipeline: idx two ahead, qn/dd one ahead
    int idx1 = nrow[0];
    uint4 qnA[4], ddA[4];
    {
        const uint4* qrow = qv + (((size_t)((b << 16) | idx1)) << 4);
        qnA[0] = qrow[quad]; qnA[1] = qrow[4 + quad];
        qnA[2] = qrow[8 + quad]; qnA[3] = qrow[12 + quad];
        const uint4* crow = qv + (((size_t)pbase) << 4);
        #pragma unroll
        for (int kt = 0; kt < 4; kt++) {
            uint4 qc = crow[kt * 4 + quad];
            ddA[kt].x = dpair(c3pk[kt].x, qc.x);
            ddA[kt].y = dpair(c3pk[kt].y, qc.y);
            ddA[kt].z = dpair(c3pk[kt].z, qc.z);
            ddA[kt].w = dpair(c3pk[kt].w, qc.w);
        }
    }
    idx1 = nrow[1];

    #pragma unroll 2
    for (int i = 0; i < 16; ++i) {
        // prefetch next point's gathers (wrap on tail: harmless reload)
        uint4 qnB[4], qcB[4];
        {
            const uint4* qrow = qv + (((size_t)((b << 16) | idx1)) << 4);
            qnB[0] = qrow[quad]; qnB[1] = qrow[4 + quad];
            qnB[2] = qrow[8 + quad]; qnB[3] = qrow[12 + quad];
            const uint4* crow = qv + (((size_t)(pbase + ((i + 1) & 15))) << 4);
            qcB[0] = crow[quad]; qcB[1] = crow[4 + quad];
            qcB[2] = crow[8 + quad]; qcB[3] = crow[12 + quad];
        }
        idx1 = nrow[(i + 2) & 15];

        f32x4 acc[8];
        #pragma unroll
        for (int nt = 0; nt < 8; nt++) acc[nt] = (f32x4){0.f, 0.f, 0.f, 0.f};
        #pragma unroll
        for (int kt = 0; kt < 4; ++kt) {
            U4 fr;
            fr.q.x = zpair(qnA[kt].x, ddA[kt].x);
            fr.q.y = zpair(qnA[kt].y, ddA[kt].y);
            fr.q.z = zpair(qnA[kt].z, ddA[kt].z);
            fr.q.w = zpair(qnA[kt].w, ddA[kt].w);
            #pragma unroll
            for (int nt = 0; nt < 8; ++nt)
                acc[nt] = __builtin_amdgcn_mfma_f32_16x16x32_bf16(fr.v, wBf[nt][kt], acc[nt], 0, 0, 0);
        }
        // max over 16 slots (rows = quad*4+r), then bf16 NE store
        size_t pout = ((size_t)(pbase + i)) << 7;
        #pragma unroll
        for (int nt = 0; nt < 8; ++nt) {
            float m = fmaxf(fmaxf(acc[nt][0], acc[nt][1]), fmaxf(acc[nt][2], acc[nt][3]));
            m = fmaxf(m, __shfl_xor(m, 16, 64));
            m = fmaxf(m, __shfl_xor(m, 32, 64));
            if (l < 16) NEg[pout + nt * 16 + l] = (u16)((__float_as_uint(m) + 0x8000u) >> 16);
        }
        #pragma unroll
        for (int kt = 0; kt < 4; kt++) {
            qnA[kt] = qnB[kt];
            ddA[kt].x = dpair(c3pk[kt].x, qcB[kt].x);
            ddA[kt].y = dpair(c3pk[kt].y, qcB[kt].y);
            ddA[kt].z = dpair(c3pk[kt].z, qcB[kt].z);
            ddA[kt].w = dpair(c3pk[kt].w, qcB[kt].w);
        }
    }
}

// ---------------- combine: out = Wcat . [NE; x_bf16; 1; 0] --------------------
__global__ __launch_bounds__(256) void combine_kernel(
    const u16* __restrict__ NEg, const float* __restrict__ x,
    const u16* __restrict__ Wcat, float* __restrict__ out)
{
    __shared__ uint4 NExq[16 * 21];   // per point: 160 bf16 (NE|x|1|0), stride 21 granules
    int tid = threadIdx.x;
    int w = tid >> 6, l = tid & 63;
    int quad = l >> 4, l15 = l & 15;

    // persistent Wcat A-fragments: A[m=o'=w*32+mt*16+l15][k=kt*32+quad*8+j]
    bf16x8 Wcf[2][5];
    #pragma unroll
    for (int mt = 0; mt < 2; mt++)
        #pragma unroll
        for (int kt = 0; kt < 5; kt++) {
            U4 u; u.q = *(const uint4*)(Wcat + (w * 32 + mt * 16 + l15) * 160 + kt * 32 + quad * 8);
            Wcf[mt][kt] = u.v;
        }

    const uint4* NEv = (const uint4*)NEg;
    for (int it = 0; it < 4; ++it) {
        int group = blockIdx.x * 4 + it;        // 8192 groups of 16 points
        int b = group >> 12;
        int n0 = (group & 4095) << 4;
        int p0 = group << 4;
        __syncthreads();   // protect NExq rewrite vs previous readers
        {
            // 256 threads = 16 pts x 16 granules (128 bf16 NE per point)
            int pt = tid >> 4, g = tid & 15;
            NExq[pt * 21 + g] = NEv[((size_t)(p0 + pt) << 4) + g];
        }
        if (tid < 16) {
            int pt = tid;
            float xv[8];
            #pragma unroll
            for (int i = 0; i < 8; i++) xv[i] = x[((b * 8 + i) << 16) + n0 + pt];
            uint4 wx;
            wx.x = pack_rne(xv[0], xv[1]); wx.y = pack_rne(xv[2], xv[3]);
            wx.z = pack_rne(xv[4], xv[5]); wx.w = pack_rne(xv[6], xv[7]);
            NExq[pt * 21 + 16] = wx;
            NExq[pt * 21 + 17] = make_uint4(0x3F80u, 0u, 0u, 0u);
            NExq[pt * 21 + 18] = make_uint4(0u, 0u, 0u, 0u);
            NExq[pt * 21 + 19] = make_uint4(0u, 0u, 0u, 0u);
        }
        __syncthreads();
        f32x4 oa[2];
        oa[0] = (f32x4){0.f, 0.f, 0.f, 0.f};
        oa[1] = (f32x4){0.f, 0.f, 0.f, 0.f};
        #pragma unroll
        for (int kt = 0; kt < 5; ++kt) {
            U4 u; u.q = NExq[l15 * 21 + kt * 4 + quad];
            oa[0] = __builtin_amdgcn_mfma_f32_16x16x32_bf16(Wcf[0][kt], u.v, oa[0], 0, 0, 0);
            oa[1] = __builtin_amdgcn_mfma_f32_16x16x32_bf16(Wcf[1][kt], u.v, oa[1], 0, 0, 0);
        }
        #pragma unroll
        for (int mt = 0; mt < 2; ++mt) {
            int ob = w * 32 + mt * 16 + quad * 4;
            #pragma unroll
            for (int r = 0; r < 4; ++r)
                out[(((b << 7) + ob + r) << 16) + n0 + l15] = oa[mt][r];
        }
    }
}

extern "C" void kernel_launch(void* const* d_in, const int* in_sizes, int n_in,
                              void* d_out, int out_size, void* d_ws, size_t ws_size,
                              hipStream_t stream) {
    const float* x   = (const float*)d_in[0];
    const int*   nbr = (const int*)d_in[1];
    const float* g1  = (const float*)d_in[2];
    const float* b1  = (const float*)d_in[3];
    const float* m1  = (const float*)d_in[4];
    const float* v1  = (const float*)d_in[5];
    const float* w1  = (const float*)d_in[6];
    const float* c1b = (const float*)d_in[7];
    const float* g2  = (const float*)d_in[8];
    const float* b2  = (const float*)d_in[9];
    const float* m2  = (const float*)d_in[10];
    const float* v2  = (const float*)d_in[11];
    const float* wA  = (const float*)d_in[12];
    const float* g3  = (const float*)d_in[13];
    const float* b3  = (const float*)d_in[14];
    const float* m3  = (const float*)d_in[15];
    const float* v3  = (const float*)d_in[16];
    const float* wB  = (const float*)d_in[17];
    const float* wf  = (const float*)d_in[18];
    const float* bfv = (const float*)d_in[19];

    float* wsF  = (float*)d_ws;
    u16*   c3bf = (u16*)((char*)d_ws + WS_C3BF);
    u16*   wBh  = (u16*)((char*)d_ws + WS_WB);
    u16*   Wcat = (u16*)((char*)d_ws + WS_WCAT);
    u16*   q    = (u16*)((char*)d_ws + WS_Q);
    u16*   NEg  = (u16*)((char*)d_ws + WS_NE);
    float* out  = (float*)d_out;

    prep_kernel<<<1, 256, 0, stream>>>(g1, b1, m1, v1, w1, c1b, g2, b2, m2, v2,
                                       wA, g3, b3, m3, v3, wB, wf, bfv, wsF, c3bf, wBh, Wcat);
    q_kernel<<<32768, 256, 0, stream>>>(x, wsF, q);
    heavy_kernel<<<8192, 64, 0, stream>>>(q, nbr, wBh, c3bf, NEg);
    combine_kernel<<<2048, 256, 0, stream>>>(NEg, x, Wcat, out);
}

// Round 6
// 354.061 us; speedup vs baseline: 2.4771x; 2.4771x over previous
//
#include <hip/hip_runtime.h>
#include <hip/hip_bf16.h>

typedef unsigned short u16;
typedef unsigned int u32;
typedef short bf16x8 __attribute__((ext_vector_type(8)));
typedef float f32x4 __attribute__((ext_vector_type(4)));

#define EPSV 1e-5f
// ws byte layout
#define WS_A3    0                       // 128*8 f32
#define WS_C3    4096                    // 128 f32
#define WS_WB    4608                    // 128*128 bf16
#define WS_WCAT  37376                   // 128*160 bf16 [wf2 | A1 | bias | 0]
#define WS_Q     78336                   // 33.55 MB bf16 q = A3@x
#define WS_QD    (78336 + 33554432)      // 33.55 MB bf16 qD = c3 - q
#define WS_NE    (78336 + 2*33554432)    // 33.55 MB bf16 NE

union U4 { uint4 q; bf16x8 v; };

__device__ __forceinline__ u16 f2bf(float f) {
    union { __hip_bfloat16 h; u16 u; } cv;
    cv.h = __float2bfloat16(f);
    return cv.u;
}
__device__ __forceinline__ u32 pack_rne(float a, float b) {
    u32 ua = __float_as_uint(a), ub = __float_as_uint(b);
    ua = ua + 0x7FFFu + ((ua >> 16) & 1u);
    ub = ub + 0x7FFFu + ((ub >> 16) & 1u);
    return (ua >> 16) | (ub & 0xFFFF0000u);
}
// z = relu(bf(a_half) + bf(d_half)), packed bf16 (round-half-up + v_perm)
__device__ __forceinline__ u32 zpair(u32 a, u32 d) {
    float lo = __uint_as_float(a << 16) + __uint_as_float(d << 16);
    float hi = __uint_as_float(a & 0xFFFF0000u) + __uint_as_float(d & 0xFFFF0000u);
    lo = fmaxf(lo, 0.f);
    hi = fmaxf(hi, 0.f);
    return __builtin_amdgcn_perm(__float_as_uint(hi) + 0x8000u,
                                 __float_as_uint(lo) + 0x8000u, 0x07060302u);
}

// ---------------- prep: fold constants (fully parallel, LDS-staged) ----------------
__global__ __launch_bounds__(256) void prep_kernel(
    const float* g1, const float* b1, const float* m1, const float* v1,
    const float* w1, const float* c1b,
    const float* g2, const float* b2, const float* m2, const float* v2,
    const float* wA,
    const float* g3, const float* b3, const float* m3, const float* v3,
    const float* wB, const float* wf, const float* bfv,
    float* ws, u16* wBh, u16* Wc)
{
    __shared__ float wfL[16384];     // wf left half, 64 KB
    __shared__ float w1s[1024];
    __shared__ float c1s[128];
    __shared__ float s1[8], be1[8], s2[8], be2[8];
    __shared__ float w1fS[128][8];
    __shared__ float cbS[128];
    int t = threadIdx.x;

    // stage (coalesced, latency-pipelined across 256 threads)
    for (int i = t; i < 16384; i += 256) wfL[i] = wf[((i >> 7) << 8) + (i & 127)];
    for (int i = t; i < 1024; i += 256) w1s[i] = w1[i];
    if (t < 128) c1s[t] = c1b[t];
    if (t < 8) {
        float s = g1[t] * rsqrtf(v1[t] + EPSV); s1[t] = s; be1[t] = b1[t] - m1[t] * s;
        float u = g2[t] * rsqrtf(v2[t] + EPSV); s2[t] = u; be2[t] = b2[t] - m2[t] * u;
    }
    __syncthreads();

    // fold wf_left @ [w1 | c1b]: thread (o, half) does 4 i's (+ cb on half 1)
    {
        int o = t >> 1, half = t & 1;
        float a0 = 0.f, a1 = 0.f, a2 = 0.f, a3 = 0.f, cb = 0.f;
        const float* wro = wfL + o * 128;
        int i0 = half * 4;
        for (int c = 0; c < 128; c++) {
            float f = wro[c];
            const float* wr = w1s + c * 8 + i0;
            a0 += f * wr[0]; a1 += f * wr[1]; a2 += f * wr[2]; a3 += f * wr[3];
            if (half) cb += f * c1s[c];
        }
        w1fS[o][i0] = a0; w1fS[o][i0 + 1] = a1; w1fS[o][i0 + 2] = a2; w1fS[o][i0 + 3] = a3;
        if (half) cbS[o] = cb;
    }
    __syncthreads();

    if (t < 128) {
        int o = t;
        float s3 = g3[o] * rsqrtf(v3[o] + EPSV);
        float be3 = b3[o] - m3[o] * s3;
        float* A3 = ws;
        float* c3 = ws + 1024;
        float csum = 0.f;
        #pragma unroll
        for (int i = 0; i < 8; i++) {
            float w = wA[o * 8 + i];
            A3[o * 8 + i] = s3 * w * s2[i] * s1[i];
            csum += w * be2[i];
        }
        c3[o] = s3 * csum + be3;

        float bs = bfv[o] + cbS[o];
        #pragma unroll
        for (int i = 0; i < 8; i++) {
            float w1f = w1fS[o][i];
            bs += w1f * be1[i];
            Wc[o * 160 + 128 + i] = f2bf(w1f * s1[i]);
        }
        Wc[o * 160 + 136] = f2bf(bs);
        for (int k = 137; k < 160; k++) Wc[o * 160 + k] = 0;
    }
    // Wcat wf2 block: 16384 elems, coalesced grid-stride
    for (int j = t; j < 16384; j += 256) {
        int o = j >> 7, c = j & 127;
        Wc[o * 160 + c] = f2bf(wf[o * 256 + 128 + c]);
    }
    // wB cast: 8192 packed u32, coalesced
    {
        u32* wbo = (u32*)wBh;
        for (int j = t; j < 8192; j += 256)
            wbo[j] = pack_rne(wB[2 * j], wB[2 * j + 1]);
    }
}

// ---------------- q = A3 @ x (bf16) and qD = c3 - q (bf16) --------------------
__global__ __launch_bounds__(256) void q_kernel(const float* __restrict__ x,
                                                const float* __restrict__ ws,
                                                u16* __restrict__ q,
                                                u16* __restrict__ qD)
{
    int t = blockIdx.x * 256 + threadIdx.x;
    int pt = t >> 6;
    int o = (t & 63) * 2;
    int b = pt >> 16, n = pt & 65535;
    const float* A3 = ws;
    float xv[8];
    #pragma unroll
    for (int i = 0; i < 8; i++) xv[i] = x[(((b << 3) + i) << 16) | n];
    float q0 = 0.f, q1 = 0.f;
    #pragma unroll
    for (int i = 0; i < 8; i++) {
        q0 += A3[o * 8 + i] * xv[i];
        q1 += A3[(o + 1) * 8 + i] * xv[i];
    }
    ((u32*)q)[t] = pack_rne(q0, q1);
    float c0 = ws[1024 + o], c1 = ws[1024 + o + 1];
    ((u32*)qD)[t] = pack_rne(c0 - q0, c1 - q1);
}

// ---------------- heavy: 1-wave blocks, barrier-free, LDS-free edge-conv ----------
// wave = 16 points; A-frag (m=slot, k=channel) built in registers from gathered
// q rows + preloaded qD center rows; wB^T fragments persistent (AGPR); 32
// MFMA/point; max over slots = rows via 2 shfl_xor; NE written bf16 to global.
// launch_bounds(64,2): 256-reg unified budget -> no spill (R5's (64,4) spilled).
__global__ __launch_bounds__(64, 2) void heavy_kernel(
    const u16* __restrict__ q, const u16* __restrict__ qD,
    const int* __restrict__ nbr, const u16* __restrict__ wBh,
    u16* __restrict__ NEg)
{
    const uint4* qv = (const uint4*)q;
    const uint4* qDv = (const uint4*)qD;
    int l = threadIdx.x;               // 0..63
    int quad = l >> 4, l15 = l & 15;

    // persistent wB^T B-fragments: B[n=o=nt*16+l15][k=kt*32+quad*8+j]
    bf16x8 wBf[8][4];
    #pragma unroll
    for (int nt = 0; nt < 8; nt++)
        #pragma unroll
        for (int kt = 0; kt < 4; kt++) {
            U4 u; u.q = *(const uint4*)(wBh + (nt * 16 + l15) * 128 + kt * 32 + quad * 8);
            wBf[nt][kt] = u.v;
        }

    int pbase = blockIdx.x * 16;       // 16 points per wave, batch-aligned
    int b = pbase >> 16;
    int n0 = pbase & 65535;
    int srow = (l15 < 15) ? l15 + 1 : 1;   // slot 15 duplicates neighbor row 1
    const int* nrow = nbr + ((((b << 4) + srow) << 16) + n0);

    // software pipeline: idx two ahead, qn/dd one ahead
    int idx1 = nrow[0];
    uint4 qnA[4], ddA[4];
    {
        const uint4* qrow = qv + (((size_t)((b << 16) | idx1)) << 4);
        qnA[0] = qrow[quad]; qnA[1] = qrow[4 + quad];
        qnA[2] = qrow[8 + quad]; qnA[3] = qrow[12 + quad];
        const uint4* drow = qDv + (((size_t)pbase) << 4);
        ddA[0] = drow[quad]; ddA[1] = drow[4 + quad];
        ddA[2] = drow[8 + quad]; ddA[3] = drow[12 + quad];
    }
    idx1 = nrow[1];

    #pragma unroll 2
    for (int i = 0; i < 16; ++i) {
        // prefetch next point's gathers (wrap on tail: harmless reload)
        uint4 qnB[4], ddB[4];
        {
            const uint4* qrow = qv + (((size_t)((b << 16) | idx1)) << 4);
            qnB[0] = qrow[quad]; qnB[1] = qrow[4 + quad];
            qnB[2] = qrow[8 + quad]; qnB[3] = qrow[12 + quad];
            const uint4* drow = qDv + (((size_t)(pbase + ((i + 1) & 15))) << 4);
            ddB[0] = drow[quad]; ddB[1] = drow[4 + quad];
            ddB[2] = drow[8 + quad]; ddB[3] = drow[12 + quad];
        }
        idx1 = nrow[(i + 2) & 15];

        f32x4 acc[8];
        #pragma unroll
        for (int nt = 0; nt < 8; nt++) acc[nt] = (f32x4){0.f, 0.f, 0.f, 0.f};
        #pragma unroll
        for (int kt = 0; kt < 4; ++kt) {
            U4 fr;
            fr.q.x = zpair(qnA[kt].x, ddA[kt].x);
            fr.q.y = zpair(qnA[kt].y, ddA[kt].y);
            fr.q.z = zpair(qnA[kt].z, ddA[kt].z);
            fr.q.w = zpair(qnA[kt].w, ddA[kt].w);
            #pragma unroll
            for (int nt = 0; nt < 8; ++nt)
                acc[nt] = __builtin_amdgcn_mfma_f32_16x16x32_bf16(fr.v, wBf[nt][kt], acc[nt], 0, 0, 0);
        }
        // max over 16 slots (rows = quad*4+r), then bf16 NE store
        size_t pout = ((size_t)(pbase + i)) << 7;
        #pragma unroll
        for (int nt = 0; nt < 8; ++nt) {
            float m = fmaxf(fmaxf(acc[nt][0], acc[nt][1]), fmaxf(acc[nt][2], acc[nt][3]));
            m = fmaxf(m, __shfl_xor(m, 16, 64));
            m = fmaxf(m, __shfl_xor(m, 32, 64));
            if (l < 16) NEg[pout + nt * 16 + l] = (u16)((__float_as_uint(m) + 0x8000u) >> 16);
        }
        #pragma unroll
        for (int kk = 0; kk < 4; kk++) { qnA[kk] = qnB[kk]; ddA[kk] = ddB[kk]; }
    }
}

// ---------------- combine: out = Wcat . [NE; x_bf16; 1; 0] --------------------
__global__ __launch_bounds__(256) void combine_kernel(
    const u16* __restrict__ NEg, const float* __restrict__ x,
    const u16* __restrict__ Wcat, float* __restrict__ out)
{
    __shared__ uint4 NExq[16 * 21];   // per point: 160 bf16 (NE|x|1|0), stride 21 granules
    int tid = threadIdx.x;
    int w = tid >> 6, l = tid & 63;
    int quad = l >> 4, l15 = l & 15;

    // persistent Wcat A-fragments: A[m=o'=w*32+mt*16+l15][k=kt*32+quad*8+j]
    bf16x8 Wcf[2][5];
    #pragma unroll
    for (int mt = 0; mt < 2; mt++)
        #pragma unroll
        for (int kt = 0; kt < 5; kt++) {
            U4 u; u.q = *(const uint4*)(Wcat + (w * 32 + mt * 16 + l15) * 160 + kt * 32 + quad * 8);
            Wcf[mt][kt] = u.v;
        }

    const uint4* NEv = (const uint4*)NEg;
    for (int it = 0; it < 4; ++it) {
        int group = blockIdx.x * 4 + it;        // 8192 groups of 16 points
        int b = group >> 12;
        int n0 = (group & 4095) << 4;
        int p0 = group << 4;
        __syncthreads();   // protect NExq rewrite vs previous readers
        {
            // 256 threads = 16 pts x 16 granules (128 bf16 NE per point)
            int pt = tid >> 4, g = tid & 15;
            NExq[pt * 21 + g] = NEv[((size_t)(p0 + pt) << 4) + g];
        }
        if (tid < 16) {
            int pt = tid;
            float xv[8];
            #pragma unroll
            for (int i = 0; i < 8; i++) xv[i] = x[((b * 8 + i) << 16) + n0 + pt];
            uint4 wx;
            wx.x = pack_rne(xv[0], xv[1]); wx.y = pack_rne(xv[2], xv[3]);
            wx.z = pack_rne(xv[4], xv[5]); wx.w = pack_rne(xv[6], xv[7]);
            NExq[pt * 21 + 16] = wx;
            NExq[pt * 21 + 17] = make_uint4(0x3F80u, 0u, 0u, 0u);
            NExq[pt * 21 + 18] = make_uint4(0u, 0u, 0u, 0u);
            NExq[pt * 21 + 19] = make_uint4(0u, 0u, 0u, 0u);
        }
        __syncthreads();
        f32x4 oa[2];
        oa[0] = (f32x4){0.f, 0.f, 0.f, 0.f};
        oa[1] = (f32x4){0.f, 0.f, 0.f, 0.f};
        #pragma unroll
        for (int kt = 0; kt < 5; ++kt) {
            U4 u; u.q = NExq[l15 * 21 + kt * 4 + quad];
            oa[0] = __builtin_amdgcn_mfma_f32_16x16x32_bf16(Wcf[0][kt], u.v, oa[0], 0, 0, 0);
            oa[1] = __builtin_amdgcn_mfma_f32_16x16x32_bf16(Wcf[1][kt], u.v, oa[1], 0, 0, 0);
        }
        #pragma unroll
        for (int mt = 0; mt < 2; ++mt) {
            int ob = w * 32 + mt * 16 + quad * 4;
            #pragma unroll
            for (int r = 0; r < 4; ++r)
                out[(((b << 7) + ob + r) << 16) + n0 + l15] = oa[mt][r];
        }
    }
}

extern "C" void kernel_launch(void* const* d_in, const int* in_sizes, int n_in,
                              void* d_out, int out_size, void* d_ws, size_t ws_size,
                              hipStream_t stream) {
    const float* x   = (const float*)d_in[0];
    const int*   nbr = (const int*)d_in[1];
    const float* g1  = (const float*)d_in[2];
    const float* b1  = (const float*)d_in[3];
    const float* m1  = (const float*)d_in[4];
    const float* v1  = (const float*)d_in[5];
    const float* w1  = (const float*)d_in[6];
    const float* c1b = (const float*)d_in[7];
    const float* g2  = (const float*)d_in[8];
    const float* b2  = (const float*)d_in[9];
    const float* m2  = (const float*)d_in[10];
    const float* v2  = (const float*)d_in[11];
    const float* wA  = (const float*)d_in[12];
    const float* g3  = (const float*)d_in[13];
    const float* b3  = (const float*)d_in[14];
    const float* m3  = (const float*)d_in[15];
    const float* v3  = (const float*)d_in[16];
    const float* wB  = (const float*)d_in[17];
    const float* wf  = (const float*)d_in[18];
    const float* bfv = (const float*)d_in[19];

    float* wsF  = (float*)d_ws;
    u16*   wBh  = (u16*)((char*)d_ws + WS_WB);
    u16*   Wcat = (u16*)((char*)d_ws + WS_WCAT);
    u16*   q    = (u16*)((char*)d_ws + WS_Q);
    u16*   qD   = (u16*)((char*)d_ws + WS_QD);
    u16*   NEg  = (u16*)((char*)d_ws + WS_NE);
    float* out  = (float*)d_out;

    prep_kernel<<<1, 256, 0, stream>>>(g1, b1, m1, v1, w1, c1b, g2, b2, m2, v2,
                                       wA, g3, b3, m3, v3, wB, wf, bfv, wsF, wBh, Wcat);
    q_kernel<<<32768, 256, 0, stream>>>(x, wsF, q, qD);
    heavy_kernel<<<8192, 64, 0, stream>>>(q, qD, nbr, wBh, NEg);
    combine_kernel<<<2048, 256, 0, stream>>>(NEg, x, Wcat, out);
}